// Round 1
// baseline (55.957 us; speedup 1.0000x reference)
//
#include <hip/hip_runtime.h>
#include <hip/hip_bf16.h>
#include <stdint.h>

// KANLinear: y[b,o] = sum_{d,k} coeff[b,d,k]*values[o,d,k] + xc@skip_w^T + skip_b
// Reformulated: Vp[o,d*16+k] = values[o,d,k] + grid[k]*skip_w[o,d]  (prep kernel)
//               y = A @ Vp^T + skip_b, A = sparse interp coeffs built on the fly.
// GEMM: M=8192, N=256, K=4096, bf16 MFMA (16x16x32), f32 accum.

#define B_ROWS 8192
#define D_DIM  256
#define O_DIM  256
#define KNOTS  16
#define KK     (D_DIM * KNOTS)   // 4096 GEMM K-dim

#define BM 64
#define BN 64
#define BK 64
#define NTHREADS 256

typedef __attribute__((ext_vector_type(8))) short bf16x8;
typedef __attribute__((ext_vector_type(4))) float f32x4;

static __device__ __forceinline__ unsigned short f2bf(float f) {
    unsigned int u = __float_as_uint(f);
    u += 0x7fffu + ((u >> 16) & 1u);   // RNE
    return (unsigned short)(u >> 16);
}

// ---------------------------------------------------------------------------
// Prep: Vp[o][kflat] = values[o][d][k] + grid[k]*skip_w[o][d], bf16,
// stored tile-blocked + XOR-swizzled:
//   tile (cblk = o>>6, kt = kflat>>6) is 64 rows(n=o&63) x 64 cols = 512 chunks
//   of 16B; logical chunk (n, k8 = (kflat>>3)&7) lives at slot n*8 + (k8^(n&7)).
// This makes GEMM B-staging a pure linear copy (global_load_lds-compatible)
// while ds_read_b128 of row-fragments is bank-conflict-free.
// ---------------------------------------------------------------------------
__global__ __launch_bounds__(256) void kan_prep(
    const float* __restrict__ values,   // [O][D][K]
    const float* __restrict__ skip_w,   // [O][D]
    const float* __restrict__ gknots,   // [K]
    unsigned short* __restrict__ Vp)    // 2 MB bf16, swizzled-tiled
{
    int tid = blockIdx.x * blockDim.x + threadIdx.x;    // 0..131071
    int e = tid * 8;                                    // element base
    int o = e >> 12;                                    // /4096
    int kflat = e & 4095;
    int od = (o << 8) | (kflat >> 4);                   // o*256 + d
    float sw = skip_w[od];
    int kmod = kflat & 15;                              // 0 or 8

    const float4* vp4 = reinterpret_cast<const float4*>(values + e);
    float4 v0 = vp4[0], v1 = vp4[1];
    float f[8] = {v0.x, v0.y, v0.z, v0.w, v1.x, v1.y, v1.z, v1.w};
    unsigned int w[4];
#pragma unroll
    for (int j = 0; j < 4; ++j) {
        float a = f[2*j]     + gknots[kmod + 2*j]     * sw;
        float b = f[2*j + 1] + gknots[kmod + 2*j + 1] * sw;
        w[j] = (unsigned int)f2bf(a) | ((unsigned int)f2bf(b) << 16);
    }

    int cblk = o >> 6, n = o & 63;
    int kt = kflat >> 6, k8 = (kflat >> 3) & 7;
    int slot = n * 8 + (k8 ^ (n & 7));
    size_t dst = (((size_t)(cblk * 64 + kt)) * 512 + (size_t)slot) * 8;
    *reinterpret_cast<uint4*>(Vp + dst) = make_uint4(w[0], w[1], w[2], w[3]);
}

// ---------------------------------------------------------------------------
// GEMM: 64x64 tile, BK=64, 4 waves of 32x32 (MI=NI=2), single-buffered LDS.
// A built on the fly from x (2 nonzero bf16 per 16-group), XOR-swizzled writes.
// B via global_load_lds (linear; source pre-swizzled by prep).
// ---------------------------------------------------------------------------
__global__ __launch_bounds__(NTHREADS, 2) void kan_gemm(
    const float* __restrict__ x,          // [B][D] f32
    const unsigned short* __restrict__ Vp,
    const float* __restrict__ skip_b,     // [O]
    float* __restrict__ out)              // [B][O] f32
{
    __shared__ unsigned short As[BM * BK];   // 8 KB, swizzled chunks
    __shared__ unsigned short Bs[BN * BK];   // 8 KB, swizzled chunks

    const int t    = threadIdx.x;
    const int lane = t & 63;
    const int wid  = t >> 6;
    const int wm   = wid >> 1;         // wave row 0..1 (32 rows each)
    const int wn   = wid & 1;          // wave col 0..1 (32 cols each)
    const int l15  = lane & 15;
    const int lhi  = lane >> 4;        // 0..3

    const int bm0  = (int)(blockIdx.x >> 2) * BM;
    const int cblk = (int)(blockIdx.x & 3);
    const int oc0  = cblk * BN;

    // A-stage mapping: one x element per thread
    const int ab  = t >> 2;            // row in tile 0..63
    const int adl = t & 3;             // d-sub 0..3 (BK/16 = 4 d per K-tile)
    const float* xp = x + (size_t)(bm0 + ab) * D_DIM + adl;

    f32x4 acc[2][2] = {};

    for (int kt = 0; kt < KK / BK; ++kt) {
        // ---- stage A: build 16 bf16 interp coeffs from one x value
        {
            float xv = xp[kt * 4];
            float xc = fminf(1.f, fmaxf(-1.f, xv));
            float tt = (xc + 1.f) * 7.5f;           // (xc+1)/h, h = 2/15
            int li = (int)tt;                        // tt in [0,15]
            li = li > 14 ? 14 : li;
            float w1 = tt - (float)li;
            unsigned short c0 = f2bf(1.f - w1), c1 = f2bf(w1);
            unsigned int lo, hi;
            if (li & 1) { lo = ((unsigned int)c0) << 16; hi = (unsigned int)c1; }
            else        { lo = (unsigned int)c0 | (((unsigned int)c1) << 16); hi = 0u; }
            int jl = li >> 1;                        // word holding lo; jl+1 gets hi
            unsigned int wd[8];
#pragma unroll
            for (int j = 0; j < 8; ++j)
                wd[j] = (j == jl) ? lo : ((j == jl + 1) ? hi : 0u);
            // chunks (ab, adl*2) and (ab, adl*2+1), swizzled
            int cA = (adl * 2)     ^ (ab & 7);
            int cB = (adl * 2 + 1) ^ (ab & 7);
            *reinterpret_cast<uint4*>((char*)As + ab * 128 + cA * 16) =
                make_uint4(wd[0], wd[1], wd[2], wd[3]);
            *reinterpret_cast<uint4*>((char*)As + ab * 128 + cB * 16) =
                make_uint4(wd[4], wd[5], wd[6], wd[7]);
        }
        // ---- stage B: linear copy of pre-swizzled 8KB tile, 16B/lane x 2
        {
            const char* tbase = (const char*)(Vp + ((size_t)(cblk * 64 + kt)) * 4096);
#pragma unroll
            for (int r = 0; r < 2; ++r) {
                const char* g = tbase + (r * 256 + t) * 16;
                unsigned ldsoff = (unsigned)(r * 256 + wid * 64) * 16u;  // wave-uniform
                __builtin_amdgcn_global_load_lds(
                    (const __attribute__((address_space(1))) unsigned int*)g,
                    (__attribute__((address_space(3))) unsigned int*)((char*)Bs + ldsoff),
                    16, 0, 0);
            }
        }
        __syncthreads();

        // ---- compute: 8 ds_read_b128 + 8 MFMA per wave
        bf16x8 af[2][2], bfg[2][2];
#pragma unroll
        for (int kh = 0; kh < 2; ++kh) {
            int k8 = kh * 4 + lhi;
#pragma unroll
            for (int mi = 0; mi < 2; ++mi) {
                int m = wm * 32 + mi * 16 + l15;
                af[mi][kh] = *reinterpret_cast<const bf16x8*>(
                    (const char*)As + m * 128 + ((k8 ^ (m & 7)) * 16));
            }
#pragma unroll
            for (int ni = 0; ni < 2; ++ni) {
                int n = wn * 32 + ni * 16 + l15;
                bfg[ni][kh] = *reinterpret_cast<const bf16x8*>(
                    (const char*)Bs + n * 128 + ((k8 ^ (n & 7)) * 16));
            }
        }
#pragma unroll
        for (int mi = 0; mi < 2; ++mi)
#pragma unroll
            for (int ni = 0; ni < 2; ++ni)
#pragma unroll
                for (int kh = 0; kh < 2; ++kh)
                    acc[mi][ni] = __builtin_amdgcn_mfma_f32_16x16x32_bf16(
                        af[mi][kh], bfg[ni][kh], acc[mi][ni], 0, 0, 0);
        __syncthreads();
    }

    // ---- epilogue: + skip_b, store f32
#pragma unroll
    for (int ni = 0; ni < 2; ++ni) {
        int col = oc0 + wn * 32 + ni * 16 + l15;
        float sb = skip_b[col];
#pragma unroll
        for (int mi = 0; mi < 2; ++mi) {
            f32x4 v = acc[mi][ni];
            int row0 = bm0 + wm * 32 + mi * 16 + lhi * 4;
#pragma unroll
            for (int r = 0; r < 4; ++r)
                out[(size_t)(row0 + r) * O_DIM + col] = v[r] + sb;
        }
    }
}

extern "C" void kernel_launch(void* const* d_in, const int* in_sizes, int n_in,
                              void* d_out, int out_size, void* d_ws, size_t ws_size,
                              hipStream_t stream) {
    const float* x      = (const float*)d_in[0];   // [8192][256]
    const float* values = (const float*)d_in[1];   // [256][256][16]
    const float* skip_w = (const float*)d_in[2];   // [256][256]
    const float* skip_b = (const float*)d_in[3];   // [256]
    const float* gknots = (const float*)d_in[4];   // [16]
    float* out = (float*)d_out;
    unsigned short* Vp = (unsigned short*)d_ws;    // 2 MB bf16 scratch

    // Prep: 1,048,576 elements, 8 per thread -> 131072 threads
    kan_prep<<<dim3(512), dim3(256), 0, stream>>>(values, skip_w, gknots, Vp);

    // GEMM: (8192/64) row tiles x (256/64) col tiles = 512 blocks
    kan_gemm<<<dim3(512), dim3(NTHREADS), 0, stream>>>(x, Vp, skip_b, out);
}

// Round 2
// 49.019 us; speedup vs baseline: 1.1415x; 1.1415x over previous
//
#include <hip/hip_runtime.h>
#include <hip/hip_bf16.h>
#include <stdint.h>

// KANLinear: y[b,o] = sum_{d,k} coeff[b,d,k]*values[o,d,k] + xc@skip_w^T + skip_b
// Reformulated: Vp[o,d*16+k] = values[o,d,k] + grid[k]*skip_w[o,d]  (prep kernel)
//               y = A @ Vp^T + skip_b, A = sparse interp coeffs built on the fly.
// GEMM: M=8192, N=256, K=4096, bf16 MFMA (16x16x32), f32 accum.
// Round 2: double-buffered LDS, BK=128, stage-before-compute pipeline,
//          one barrier per K-step, register x-prefetch.

#define D_DIM  256
#define O_DIM  256
#define KK     4096
#define BM     64
#define BN     64
#define BK     128
#define NT     (KK / BK)      // 32 K-steps
#define NTHREADS 256

typedef __attribute__((ext_vector_type(8))) short bf16x8;
typedef __attribute__((ext_vector_type(4))) float f32x4;

// ---------------------------------------------------------------------------
// Prep: Vp[o][kflat] = values[o][d][k] + grid[k]*skip_w[o][d], bf16,
// tile-blocked for the GEMM's BK=128 tiles + XOR-pre-swizzled:
//   tile (cblk = o>>6, kt = kflat>>7) = 64 rows(n=o&63) x 128 cols
//   = 1024 chunks of 16B; logical chunk (n, k8=(kflat>>3)&15) at slot
//   n*16 + (k8 ^ (n&7)).
// GEMM B-staging is then a pure linear global_load_lds copy while
// ds_read_b128 of row-fragments is bank-conflict-free (rule 21: inverse-
// swizzled source + swizzled read).
// ---------------------------------------------------------------------------
__global__ __launch_bounds__(256) void kan_prep(
    const float* __restrict__ values,   // [O][D][K]
    const float* __restrict__ skip_w,   // [O][D]
    const float* __restrict__ gknots,   // [K]
    unsigned short* __restrict__ Vp)    // 2 MB bf16, swizzled-tiled
{
    int tid = blockIdx.x * blockDim.x + threadIdx.x;    // 0..131071
    int e = tid * 8;                                    // element base
    int o = e >> 12;                                    // /4096
    int kflat = e & 4095;
    int od = (o << 8) | (kflat >> 4);                   // o*256 + d
    float sw = skip_w[od];
    int kmod = kflat & 15;                              // 0 or 8

    const float4* vp4 = reinterpret_cast<const float4*>(values + e);
    float4 v0 = vp4[0], v1 = vp4[1];
    float f[8] = {v0.x, v0.y, v0.z, v0.w, v1.x, v1.y, v1.z, v1.w};
    unsigned int w[4];
#pragma unroll
    for (int j = 0; j < 4; ++j) {
        float2 ab;
        ab.x = f[2*j]     + gknots[kmod + 2*j]     * sw;
        ab.y = f[2*j + 1] + gknots[kmod + 2*j + 1] * sw;
        __hip_bfloat162 p2 = __float22bfloat162_rn(ab);
        __builtin_memcpy(&w[j], &p2, 4);
    }

    int cblk = o >> 6, n = o & 63;
    int kt = kflat >> 7;                 // BK=128 tile index, 0..31
    int k8 = (kflat >> 3) & 15;          // chunk col within tile, 0..15
    int slot = n * 16 + (k8 ^ (n & 7));
    size_t dst = (((size_t)(cblk * NT + kt)) * 1024 + (size_t)slot) * 8;
    *reinterpret_cast<uint4*>(Vp + dst) = make_uint4(w[0], w[1], w[2], w[3]);
}

// ---------------------------------------------------------------------------
// GEMM: 64x64 tile, BK=128, 4 waves of 32x32, double-buffered LDS.
// Per iter: issue B-DMA(t+1) -> ds_read frags(t) -> A-build+write(t+1)
//           -> 16 MFMA -> barrier.
// ---------------------------------------------------------------------------
__global__ __launch_bounds__(NTHREADS, 2) void kan_gemm(
    const float* __restrict__ x,          // [B][D] f32
    const unsigned short* __restrict__ Vp,
    const float* __restrict__ skip_b,     // [O]
    float* __restrict__ out)              // [B][O] f32
{
    __shared__ unsigned short As[2][BM * BK];   // 2 x 16 KB
    __shared__ unsigned short Bs[2][BN * BK];   // 2 x 16 KB

    const int t    = threadIdx.x;
    const int lane = t & 63;
    const int wid  = t >> 6;
    const int wm   = wid >> 1;         // wave row 0..1 (32 rows each)
    const int wn   = wid & 1;          // wave col 0..1 (32 cols each)
    const int l15  = lane & 15;
    const int lhi  = lane >> 4;        // 0..3

    const int bm0  = (int)(blockIdx.x >> 2) * BM;
    const int cblk = (int)(blockIdx.x & 3);
    const int oc0  = cblk * BN;

    // A-stage mapping: thread handles rows ab, d-locals {adl, adl+4} per iter
    const int ab  = t >> 2;            // row in tile 0..63
    const int adl = t & 3;
    const float* xp = x + (size_t)(bm0 + ab) * D_DIM + adl;

    char* arow0 = (char*)&As[0][0] + ab * 256;
    char* arow1 = (char*)&As[1][0] + ab * 256;
    const int cs0 = ((2 * adl)     ^ (ab & 7)) * 16;
    const int cs1 = ((2 * adl + 1) ^ (ab & 7)) * 16;
    const int cs2 = ((2 * adl + 8) ^ (ab & 7)) * 16;
    const int cs3 = ((2 * adl + 9) ^ (ab & 7)) * 16;

    f32x4 acc[2][2] = {};

    // one x value -> 16 bf16 interp coeffs (8 dwords), pair at knots li,li+1
    auto buildwd = [&](float xv, unsigned int* wd) {
        float xc = fminf(1.f, fmaxf(-1.f, xv));
        float tt = (xc + 1.f) * 7.5f;            // (xc - g0)/h, h = 2/15
        int li = (int)tt;
        li = li > 14 ? 14 : li;
        float w1 = tt - (float)li;
        float2 cw; cw.x = 1.f - w1; cw.y = w1;
        __hip_bfloat162 p2 = __float22bfloat162_rn(cw);   // v_cvt_pk_bf16_f32
        unsigned int pk;
        __builtin_memcpy(&pk, &p2, 4);
        unsigned long long w64 = (unsigned long long)pk << ((li & 1) * 16);
        unsigned int lo = (unsigned int)w64;
        unsigned int hi = (unsigned int)(w64 >> 32);
        int jl = li >> 1;
#pragma unroll
        for (int j = 0; j < 8; ++j)
            wd[j] = (j == jl) ? lo : ((j == jl + 1) ? hi : 0u);
    };

    auto stageA = [&](char* arow, float xv0, float xv1) {
        unsigned int wd[8];
        buildwd(xv0, wd);
        *reinterpret_cast<uint4*>(arow + cs0) = make_uint4(wd[0], wd[1], wd[2], wd[3]);
        *reinterpret_cast<uint4*>(arow + cs1) = make_uint4(wd[4], wd[5], wd[6], wd[7]);
        buildwd(xv1, wd);
        *reinterpret_cast<uint4*>(arow + cs2) = make_uint4(wd[0], wd[1], wd[2], wd[3]);
        *reinterpret_cast<uint4*>(arow + cs3) = make_uint4(wd[4], wd[5], wd[6], wd[7]);
    };

    auto stageB = [&](int buf, int ktile) {
        const char* tb = (const char*)(Vp + ((size_t)(cblk * NT + ktile)) * (BN * BK));
        char* lb = (char*)&Bs[buf][0];
#pragma unroll
        for (int r = 0; r < 4; ++r) {
            const char* g = tb + (r * 256 + t) * 16;
            unsigned ldsoff = (unsigned)((r * 256 + wid * 64) * 16);  // wave-uniform base
            __builtin_amdgcn_global_load_lds(
                (const __attribute__((address_space(1))) unsigned int*)g,
                (__attribute__((address_space(3))) unsigned int*)(lb + ldsoff),
                16, 0, 0);
        }
    };

    // ---- prologue: stage tile 0, prefetch x for tile 1
    float xn0 = xp[0], xn1 = xp[4];
    stageB(0, 0);
    stageA(arow0, xn0, xn1);
    xn0 = xp[8]; xn1 = xp[12];
    __syncthreads();

    for (int kt = 0; kt < NT; ++kt) {
        const int cur = kt & 1;

        // 1. issue next B-tile DMA early (hides under this iter's compute)
        if (kt + 1 < NT) stageB(cur ^ 1, kt + 1);

        // 2. fragment reads of current tile
        bf16x8 af[2][4], bg[2][4];
        const char* Ab = (const char*)&As[cur][0];
        const char* Bb = (const char*)&Bs[cur][0];
#pragma unroll
        for (int kh = 0; kh < 4; ++kh) {
            int k8 = kh * 4 + lhi;
#pragma unroll
            for (int mi = 0; mi < 2; ++mi) {
                int m = wm * 32 + mi * 16 + l15;
                af[mi][kh] = *reinterpret_cast<const bf16x8*>(
                    Ab + m * 256 + ((k8 ^ (m & 7)) * 16));
            }
#pragma unroll
            for (int ni = 0; ni < 2; ++ni) {
                int n = wn * 32 + ni * 16 + l15;
                bg[ni][kh] = *reinterpret_cast<const bf16x8*>(
                    Bb + n * 256 + ((k8 ^ (n & 7)) * 16));
            }
        }

        // 3. A-build for next tile (VALU overlaps ds_read latency)
        if (kt + 1 < NT) {
            stageA(cur ? arow0 : arow1, xn0, xn1);
            if (kt + 2 < NT) {
                xn0 = xp[(kt + 2) * 8];
                xn1 = xp[(kt + 2) * 8 + 4];
            }
        }

        // 4. 16 MFMA
#pragma unroll
        for (int mi = 0; mi < 2; ++mi)
#pragma unroll
            for (int ni = 0; ni < 2; ++ni)
#pragma unroll
                for (int kh = 0; kh < 4; ++kh)
                    acc[mi][ni] = __builtin_amdgcn_mfma_f32_16x16x32_bf16(
                        af[mi][kh], bg[ni][kh], acc[mi][ni], 0, 0, 0);

        // 5. single barrier per iter (drains DMA + A-writes)
        __syncthreads();
    }

    // ---- epilogue: + skip_b, store f32
#pragma unroll
    for (int ni = 0; ni < 2; ++ni) {
        int col = oc0 + wn * 32 + ni * 16 + l15;
        float sb = skip_b[col];
#pragma unroll
        for (int mi = 0; mi < 2; ++mi) {
            f32x4 v = acc[mi][ni];
            int row0 = bm0 + wm * 32 + mi * 16 + lhi * 4;
#pragma unroll
            for (int r = 0; r < 4; ++r)
                out[(size_t)(row0 + r) * O_DIM + col] = v[r] + sb;
        }
    }
}

extern "C" void kernel_launch(void* const* d_in, const int* in_sizes, int n_in,
                              void* d_out, int out_size, void* d_ws, size_t ws_size,
                              hipStream_t stream) {
    const float* x      = (const float*)d_in[0];   // [8192][256]
    const float* values = (const float*)d_in[1];   // [256][256][16]
    const float* skip_w = (const float*)d_in[2];   // [256][256]
    const float* skip_b = (const float*)d_in[3];   // [256]
    const float* gknots = (const float*)d_in[4];   // [16]
    float* out = (float*)d_out;
    unsigned short* Vp = (unsigned short*)d_ws;    // 2 MB bf16 scratch

    // Prep: 1,048,576 elements, 8 per thread -> 131072 threads
    kan_prep<<<dim3(512), dim3(256), 0, stream>>>(values, skip_w, gknots, Vp);

    // GEMM: (8192/64) row tiles x 4 col tiles = 512 blocks
    kan_gemm<<<dim3(512), dim3(NTHREADS), 0, stream>>>(x, Vp, skip_b, out);
}